// Round 11
// baseline (193.027 us; speedup 1.0000x reference)
//
#include <hip/hip_runtime.h>

// LJ 12-6 over a neighbor list — round 11: R10's fused 6x6-xy-cell filter
// + 2-stage software pipeline.
// R10 (73.5 us steady) decomposed as SUM of pipes (gathers 67k + VALU 47k +
// LDS 25k + idx 19k + atomics 13k cyc/CU ~= 176k measured) with no pipe >40%
// busy -> per-wave serial chain is the binding constraint (16 waves can't
// cover it). Pipeline: gathers(B) -> idx-load(C) -> compute(B) [vmcnt leaves
// C in flight] -> filter(C) [C ~400cyc old] -> rotate.

typedef int   v4i __attribute__((ext_vector_type(4)));
typedef float v4f __attribute__((ext_vector_type(4)));

#define GRP    8
#define WGT    1024
#define NWG_F  256

__global__ void __launch_bounds__(256) pad_R_kernel(
    const float* __restrict__ R, v4f* __restrict__ Rp, int n_atoms)
{
    int a = blockIdx.x * blockDim.x + threadIdx.x;
    if (a < n_atoms) {
        v4f v;
        v.x = R[3 * a + 0];
        v.y = R[3 * a + 1];
        v.z = R[3 * a + 2];
        v.w = 0.0f;
        Rp[a] = v;  // 16B aligned: single-transaction gathers
    }
}

// Pack 6-bit cell ids (cx | cy<<3, cells of size cutoff, clamped to 0..7):
// thread t owns atoms [16t,16t+16) -> 96 bits -> 3 words (no write races).
__global__ void __launch_bounds__(256) cell_kernel(
    const float* __restrict__ R, const float* __restrict__ cut_p,
    unsigned* __restrict__ packed, int n_atoms)
{
    int t = blockIdx.x * blockDim.x + threadIdx.x;
    int n_thr = (n_atoms + 15) >> 4;
    if (t >= n_thr) return;
    const float inv_cut = 1.0f / cut_p[0];
    int a0 = t << 4;
    unsigned w[3] = {0u, 0u, 0u};
#pragma unroll
    for (int k = 0; k < 16; ++k) {
        int a = a0 + k;
        unsigned c = 0u;
        if (a < n_atoms) {
            int cx = min(7, max(0, (int)(R[3 * a + 0] * inv_cut)));
            int cy = min(7, max(0, (int)(R[3 * a + 1] * inv_cut)));
            c = (unsigned)(cx | (cy << 3));
        }
        int bit = 6 * k, word = bit >> 5, off = bit & 31;
        w[word] |= c << off;
        if (off > 26) w[word + 1] |= c >> (32 - off);
    }
    packed[3 * t + 0] = w[0];
    packed[3 * t + 1] = w[1];
    packed[3 * t + 2] = w[2];
}

__device__ __forceinline__ unsigned cell6(const unsigned char* c8, unsigned a) {
    unsigned bit = a * 6u;
    unsigned by  = bit >> 3;
    unsigned v   = (unsigned)c8[by] | ((unsigned)c8[by + 1] << 8);
    return (v >> (bit & 7u)) & 63u;
}

__device__ __forceinline__ void lj_body(
    v4f A, v4f B, float eps, float s2, float cut2, int gi,
    float* __restrict__ energy, float* __restrict__ forces)
{
    const float dx = A.x - B.x, dy = A.y - B.y, dz = A.z - B.z;
    const float r2 = dx * dx + dy * dy + dz * dz;
    if (r2 < cut2 && r2 > 1e-10f) {
        const float inv  = 1.0f / r2;
        const float sr2  = s2 * inv;
        const float sr6  = sr2 * sr2 * sr2;
        const float sr12 = sr6 * sr6;
        const float e    = 2.0f * eps * (sr12 - sr6);              // 0.5 * 4eps
        const float f    = 24.0f * eps * (2.0f * sr12 - sr6) * inv;
        atomicAdd(&energy[gi], e);
        atomicAdd(&forces[3 * gi + 0], f * dx);
        atomicAdd(&forces[3 * gi + 1], f * dy);
        atomicAdd(&forces[3 * gi + 2], f * dz);
    }
}

__global__ void __launch_bounds__(WGT) lj_fused_kernel(
    const v4f* __restrict__ Rp,
    const unsigned* __restrict__ packed,
    const int* __restrict__ idx_i,
    const int* __restrict__ idx_j,
    const float* __restrict__ eps_p,
    const float* __restrict__ sig_p,
    const float* __restrict__ cut_p,
    float* __restrict__ energy,
    float* __restrict__ forces,
    int n_pairs, int pk_words, int chunk)
{
    extern __shared__ unsigned lds[];
    for (int w = threadIdx.x; w < pk_words; w += WGT)
        lds[w] = packed[w];
    __syncthreads();
    const unsigned char* c8 = (const unsigned char*)lds;

    const float eps  = eps_p[0];
    const float sig  = sig_p[0];
    const float cut  = cut_p[0];
    const float s2   = sig * sig;
    const float cut2 = cut * cut;

    const int cs   = blockIdx.x * chunk;
    const int ce   = min(cs + chunk, n_pairs);
    const int step = WGT * GRP;

    int p = cs + threadIdx.x * GRP;
    if (p >= ce) return;

    int isB[GRP], jsB[GRP], isC[GRP], jsC[GRP];

    // ---- prologue: load + filter block B ----
    {
        if (p + GRP <= n_pairs) {
            v4i a0 = __builtin_nontemporal_load((const v4i*)idx_i + (p >> 2));
            v4i a1 = __builtin_nontemporal_load((const v4i*)idx_i + (p >> 2) + 1);
            v4i b0 = __builtin_nontemporal_load((const v4i*)idx_j + (p >> 2));
            v4i b1 = __builtin_nontemporal_load((const v4i*)idx_j + (p >> 2) + 1);
            isB[0] = a0.x; isB[1] = a0.y; isB[2] = a0.z; isB[3] = a0.w;
            isB[4] = a1.x; isB[5] = a1.y; isB[6] = a1.z; isB[7] = a1.w;
            jsB[0] = b0.x; jsB[1] = b0.y; jsB[2] = b0.z; jsB[3] = b0.w;
            jsB[4] = b1.x; jsB[5] = b1.y; jsB[6] = b1.z; jsB[7] = b1.w;
        } else {
#pragma unroll
            for (int k = 0; k < GRP; ++k) {
                bool v = (p + k < n_pairs);
                isB[k] = v ? idx_i[p + k] : 0;
                jsB[k] = v ? idx_j[p + k] : 0;
                // padded entries: i==j==0 -> r2==0 -> rejected by r2>1e-10
            }
        }
    }
    unsigned mB = 0u;
#pragma unroll
    for (int k = 0; k < GRP; ++k) {
        unsigned ci = cell6(c8, (unsigned)isB[k]);
        unsigned cj = cell6(c8, (unsigned)jsB[k]);
        int ddx = (int)(ci & 7u) - (int)(cj & 7u);
        int ddy = (int)(ci >> 3) - (int)(cj >> 3);
        bool ok = ((unsigned)(ddx + 1) <= 2u) & ((unsigned)(ddy + 1) <= 2u);
        if (ok) mB |= (1u << k);
    }

    // ---- steady-state pipeline ----
    for (;;) {
        // 1) issue masked gathers for B (before idx C so compute's vmcnt
        //    wait can leave the idx loads in flight)
        v4f Ri[GRP], Rj[GRP];
#pragma unroll
        for (int k = 0; k < GRP; ++k)
            if (mB & (1u << k)) { Ri[k] = Rp[isB[k]]; Rj[k] = Rp[jsB[k]]; }

        // 2) issue idx loads for C
        const int pn = p + step;
        const bool have_next = pn < ce;
        if (have_next) {
            if (pn + GRP <= n_pairs) {
                v4i a0 = __builtin_nontemporal_load((const v4i*)idx_i + (pn >> 2));
                v4i a1 = __builtin_nontemporal_load((const v4i*)idx_i + (pn >> 2) + 1);
                v4i b0 = __builtin_nontemporal_load((const v4i*)idx_j + (pn >> 2));
                v4i b1 = __builtin_nontemporal_load((const v4i*)idx_j + (pn >> 2) + 1);
                isC[0] = a0.x; isC[1] = a0.y; isC[2] = a0.z; isC[3] = a0.w;
                isC[4] = a1.x; isC[5] = a1.y; isC[6] = a1.z; isC[7] = a1.w;
                jsC[0] = b0.x; jsC[1] = b0.y; jsC[2] = b0.z; jsC[3] = b0.w;
                jsC[4] = b1.x; jsC[5] = b1.y; jsC[6] = b1.z; jsC[7] = b1.w;
            } else {
#pragma unroll
                for (int k = 0; k < GRP; ++k) {
                    bool v = (pn + k < n_pairs);
                    isC[k] = v ? idx_i[pn + k] : 0;
                    jsC[k] = v ? idx_j[pn + k] : 0;
                }
            }
        }

        // 3) compute B (waits only on the gathers)
#pragma unroll
        for (int k = 0; k < GRP; ++k)
            if (mB & (1u << k))
                lj_body(Ri[k], Rj[k], eps, s2, cut2, isB[k], energy, forces);

        if (!have_next) break;

        // 4) filter C (LDS; idx C has had the whole compute to arrive)
        unsigned mC = 0u;
#pragma unroll
        for (int k = 0; k < GRP; ++k) {
            unsigned ci = cell6(c8, (unsigned)isC[k]);
            unsigned cj = cell6(c8, (unsigned)jsC[k]);
            int ddx = (int)(ci & 7u) - (int)(cj & 7u);
            int ddy = (int)(ci >> 3) - (int)(cj >> 3);
            bool ok = ((unsigned)(ddx + 1) <= 2u) & ((unsigned)(ddy + 1) <= 2u);
            if (ok) mC |= (1u << k);
        }

        // 5) rotate C -> B
        mB = mC;
#pragma unroll
        for (int k = 0; k < GRP; ++k) { isB[k] = isC[k]; jsB[k] = jsC[k]; }
        p = pn;
    }
}

// ---------- fallback (R2 structure, 131 us) if ws/LDS insufficient ----------
#define PPT 8
__global__ void __launch_bounds__(256) lj_pairs_fb_kernel(
    const v4f* __restrict__ Rp,
    const v4i* __restrict__ idx_i4, const v4i* __restrict__ idx_j4,
    const float* __restrict__ eps_p, const float* __restrict__ sig_p,
    const float* __restrict__ cut_p,
    float* __restrict__ energy, float* __restrict__ forces, int n_oct)
{
    int t = blockIdx.x * blockDim.x + threadIdx.x;
    if (t >= n_oct) return;
    const float eps  = eps_p[0];
    const float sig  = sig_p[0];
    const float cut  = cut_p[0];
    const float s2   = sig * sig;
    const float cut2 = cut * cut;
    v4i ii0 = __builtin_nontemporal_load(idx_i4 + 2 * t);
    v4i ii1 = __builtin_nontemporal_load(idx_i4 + 2 * t + 1);
    v4i jj0 = __builtin_nontemporal_load(idx_j4 + 2 * t);
    v4i jj1 = __builtin_nontemporal_load(idx_j4 + 2 * t + 1);
    int is[PPT] = { ii0.x, ii0.y, ii0.z, ii0.w, ii1.x, ii1.y, ii1.z, ii1.w };
    int js[PPT] = { jj0.x, jj0.y, jj0.z, jj0.w, jj1.x, jj1.y, jj1.z, jj1.w };
    v4f Ri[PPT], Rj[PPT];
#pragma unroll
    for (int k = 0; k < PPT; ++k) Ri[k] = Rp[is[k]];
#pragma unroll
    for (int k = 0; k < PPT; ++k) Rj[k] = Rp[js[k]];
#pragma unroll
    for (int k = 0; k < PPT; ++k)
        lj_body(Ri[k], Rj[k], eps, s2, cut2, is[k], energy, forces);
}

__global__ void lj_pairs_fb_tail_kernel(
    const v4f* __restrict__ Rp,
    const int* __restrict__ idx_i, const int* __restrict__ idx_j,
    const float* __restrict__ eps_p, const float* __restrict__ sig_p,
    const float* __restrict__ cut_p,
    float* __restrict__ energy, float* __restrict__ forces,
    int start, int n_pairs)
{
    int p = start + blockIdx.x * blockDim.x + threadIdx.x;
    if (p >= n_pairs) return;
    const float eps = eps_p[0];
    const float sig = sig_p[0];
    const float cut = cut_p[0];
    lj_body(Rp[idx_i[p]], Rp[idx_j[p]], eps, sig * sig, cut * cut,
            idx_i[p], energy, forces);
}
// -----------------------------------------------------------------------------

extern "C" void kernel_launch(void* const* d_in, const int* in_sizes, int n_in,
                              void* d_out, int out_size, void* d_ws, size_t ws_size,
                              hipStream_t stream) {
    const float* R     = (const float*)d_in[0];
    const float* eps_p = (const float*)d_in[1];
    const float* sig_p = (const float*)d_in[2];
    const float* cut_p = (const float*)d_in[3];
    const int*   idx_i = (const int*)d_in[4];
    const int*   idx_j = (const int*)d_in[5];

    const int n_atoms = in_sizes[0] / 3;
    const int n_pairs = in_sizes[4];

    float* energy = (float*)d_out;
    float* forces = (float*)d_out + n_atoms;

    // d_out re-poisoned 0xAA before every timed call — zero it.
    (void)hipMemsetAsync(d_out, 0, (size_t)out_size * sizeof(float), stream);

    // ws layout: [Rp float4][packed 6-bit cell table]
    char* ws = (char*)d_ws;
    const size_t rp_b     = (((size_t)n_atoms * 16) + 255) & ~(size_t)255;
    const int    n_thr    = (n_atoms + 15) >> 4;
    const int    pk_words = 3 * n_thr + 1;               // +1 word read pad
    const size_t pk_b     = (((size_t)pk_words * 4) + 255) & ~(size_t)255;
    const size_t lds_b    = (((size_t)pk_words * 4) + 15) & ~(size_t)15;

    const bool have_rp    = ws_size >= rp_b;
    const bool use_filter = have_rp && (ws_size >= rp_b + pk_b)
                            && (lds_b <= 160000);

    v4f*      Rp     = (v4f*)ws;
    unsigned* packed = (unsigned*)(ws + rp_b);

    if (have_rp) {
        int blocks = (n_atoms + 255) / 256;
        pad_R_kernel<<<blocks, 256, 0, stream>>>(R, Rp, n_atoms);
    }

    if (use_filter) {
        int cblocks = (n_thr + 255) / 256;
        cell_kernel<<<cblocks, 256, 0, stream>>>(R, cut_p, packed, n_atoms);

        (void)hipFuncSetAttribute((const void*)lj_fused_kernel,
                                  hipFuncAttributeMaxDynamicSharedMemorySize,
                                  (int)lds_b);

        // one WG per CU: table loaded into LDS exactly once per CU
        int chunk = (((n_pairs + NWG_F - 1) / NWG_F) + GRP - 1) & ~(GRP - 1);
        lj_fused_kernel<<<NWG_F, WGT, lds_b, stream>>>(
            Rp, packed, idx_i, idx_j, eps_p, sig_p, cut_p,
            energy, forces, n_pairs, pk_words, chunk);
    } else {
        const int n_oct = n_pairs / PPT;
        const int start = n_oct * PPT;
        if (n_oct > 0) {
            int blocks = (n_oct + 255) / 256;
            lj_pairs_fb_kernel<<<blocks, 256, 0, stream>>>(
                Rp, (const v4i*)idx_i, (const v4i*)idx_j,
                eps_p, sig_p, cut_p, energy, forces, n_oct);
        }
        if (start < n_pairs) {
            lj_pairs_fb_tail_kernel<<<1, 64, 0, stream>>>(
                Rp, idx_i, idx_j, eps_p, sig_p, cut_p,
                energy, forces, start, n_pairs);
        }
    }
}

// Round 12
// 192.890 us; speedup vs baseline: 1.0007x; 1.0007x over previous
//
#include <hip/hip_runtime.h>

// LJ 12-6 over a neighbor list — round 12: select-indexed UNCONDITIONAL
// gathers. R11's masked gathers (`if (bit) load`) compile to exec-branches
// with s_cbranch_execz -> dynamic vmcnt -> compiler forced to vmcnt(0)
// before first use -> no pipelining (R11 neutral, VGPR stuck at 64).
// Fix: ii = pass ? idx : 0; unconditional Rp[ii] load. Failing lanes all
// hit Rp[0] (same-address broadcast = 1 L1-hot transaction), vmcnt becomes
// static, and dummy pairs self-reject via r2==0 < 1e-10 (same rule the
// reference uses for coincident atoms).

typedef int   v4i __attribute__((ext_vector_type(4)));
typedef float v4f __attribute__((ext_vector_type(4)));

#define GRP    8
#define WGT    1024
#define NWG_F  256

__global__ void __launch_bounds__(256) pad_R_kernel(
    const float* __restrict__ R, v4f* __restrict__ Rp, int n_atoms)
{
    int a = blockIdx.x * blockDim.x + threadIdx.x;
    if (a < n_atoms) {
        v4f v;
        v.x = R[3 * a + 0];
        v.y = R[3 * a + 1];
        v.z = R[3 * a + 2];
        v.w = 0.0f;
        Rp[a] = v;  // 16B aligned: single-transaction gathers
    }
}

// Pack 6-bit cell ids (cx | cy<<3, cells of size cutoff, clamped to 0..7):
// thread t owns atoms [16t,16t+16) -> 96 bits -> 3 words (no write races).
__global__ void __launch_bounds__(256) cell_kernel(
    const float* __restrict__ R, const float* __restrict__ cut_p,
    unsigned* __restrict__ packed, int n_atoms)
{
    int t = blockIdx.x * blockDim.x + threadIdx.x;
    int n_thr = (n_atoms + 15) >> 4;
    if (t >= n_thr) return;
    const float inv_cut = 1.0f / cut_p[0];
    int a0 = t << 4;
    unsigned w[3] = {0u, 0u, 0u};
#pragma unroll
    for (int k = 0; k < 16; ++k) {
        int a = a0 + k;
        unsigned c = 0u;
        if (a < n_atoms) {
            int cx = min(7, max(0, (int)(R[3 * a + 0] * inv_cut)));
            int cy = min(7, max(0, (int)(R[3 * a + 1] * inv_cut)));
            c = (unsigned)(cx | (cy << 3));
        }
        int bit = 6 * k, word = bit >> 5, off = bit & 31;
        w[word] |= c << off;
        if (off > 26) w[word + 1] |= c >> (32 - off);
    }
    packed[3 * t + 0] = w[0];
    packed[3 * t + 1] = w[1];
    packed[3 * t + 2] = w[2];
}

__device__ __forceinline__ unsigned cell6(const unsigned char* c8, unsigned a) {
    unsigned bit = a * 6u;
    unsigned by  = bit >> 3;
    unsigned v   = (unsigned)c8[by] | ((unsigned)c8[by + 1] << 8);
    return (v >> (bit & 7u)) & 63u;
}

__device__ __forceinline__ void lj_body(
    v4f A, v4f B, float eps, float s2, float cut2, int gi,
    float* __restrict__ energy, float* __restrict__ forces)
{
    const float dx = A.x - B.x, dy = A.y - B.y, dz = A.z - B.z;
    const float r2 = dx * dx + dy * dy + dz * dz;
    // dummy (select-zeroed) pairs have A==B -> r2==0 -> rejected here,
    // exactly like the reference's coincident-atom mask
    if (r2 < cut2 && r2 > 1e-10f) {
        const float inv  = 1.0f / r2;
        const float sr2  = s2 * inv;
        const float sr6  = sr2 * sr2 * sr2;
        const float sr12 = sr6 * sr6;
        const float e    = 2.0f * eps * (sr12 - sr6);              // 0.5 * 4eps
        const float f    = 24.0f * eps * (2.0f * sr12 - sr6) * inv;
        atomicAdd(&energy[gi], e);
        atomicAdd(&forces[3 * gi + 0], f * dx);
        atomicAdd(&forces[3 * gi + 1], f * dy);
        atomicAdd(&forces[3 * gi + 2], f * dz);
    }
}

__global__ void __launch_bounds__(WGT) lj_fused_kernel(
    const v4f* __restrict__ Rp,
    const unsigned* __restrict__ packed,
    const int* __restrict__ idx_i,
    const int* __restrict__ idx_j,
    const float* __restrict__ eps_p,
    const float* __restrict__ sig_p,
    const float* __restrict__ cut_p,
    float* __restrict__ energy,
    float* __restrict__ forces,
    int n_pairs, int pk_words, int chunk)
{
    extern __shared__ unsigned lds[];
    for (int w = threadIdx.x; w < pk_words; w += WGT)
        lds[w] = packed[w];
    __syncthreads();
    const unsigned char* c8 = (const unsigned char*)lds;

    const float eps  = eps_p[0];
    const float sig  = sig_p[0];
    const float cut  = cut_p[0];
    const float s2   = sig * sig;
    const float cut2 = cut * cut;

    const int cs = blockIdx.x * chunk;
    const int ce = min(cs + chunk, n_pairs);

    for (int p = cs + threadIdx.x * GRP; p < ce; p += WGT * GRP) {
        int is8[GRP], js8[GRP];
        if (p + GRP <= n_pairs) {   // p % 8 == 0 -> int4-aligned fast path
            v4i a0 = __builtin_nontemporal_load((const v4i*)idx_i + (p >> 2));
            v4i a1 = __builtin_nontemporal_load((const v4i*)idx_i + (p >> 2) + 1);
            v4i b0 = __builtin_nontemporal_load((const v4i*)idx_j + (p >> 2));
            v4i b1 = __builtin_nontemporal_load((const v4i*)idx_j + (p >> 2) + 1);
            is8[0] = a0.x; is8[1] = a0.y; is8[2] = a0.z; is8[3] = a0.w;
            is8[4] = a1.x; is8[5] = a1.y; is8[6] = a1.z; is8[7] = a1.w;
            js8[0] = b0.x; js8[1] = b0.y; js8[2] = b0.z; js8[3] = b0.w;
            js8[4] = b1.x; js8[5] = b1.y; js8[6] = b1.z; js8[7] = b1.w;
        } else {
#pragma unroll
            for (int k = 0; k < GRP; ++k) {
                bool v = (p + k < n_pairs);
                is8[k] = v ? idx_i[p + k] : 0;
                js8[k] = v ? idx_j[p + k] : 0;
                // padded entries: i==j==0 -> r2==0 -> rejected by r2>1e-10
            }
        }

        // Phase 1: LDS xy-cell filter -> select gather index (no branches)
        int gi8[GRP], gj8[GRP];
#pragma unroll
        for (int k = 0; k < GRP; ++k) {
            unsigned ci = cell6(c8, (unsigned)is8[k]);
            unsigned cj = cell6(c8, (unsigned)js8[k]);
            int ddx = (int)(ci & 7u) - (int)(cj & 7u);
            int ddy = (int)(ci >> 3) - (int)(cj >> 3);
            bool ok = ((unsigned)(ddx + 1) <= 2u) & ((unsigned)(ddy + 1) <= 2u);
            gi8[k] = ok ? is8[k] : 0;   // fail -> both read Rp[0]:
            gj8[k] = ok ? js8[k] : 0;   // same-address broadcast, L1-hot
        }

        // Phase 2: UNCONDITIONAL gathers — static vmcnt, compiler batches
        // all 16 loads and pipelines precise vmcnt(N) waits
        v4f Ri[GRP], Rj[GRP];
#pragma unroll
        for (int k = 0; k < GRP; ++k) Ri[k] = Rp[gi8[k]];
#pragma unroll
        for (int k = 0; k < GRP; ++k) Rj[k] = Rp[gj8[k]];

        // Phase 3: LJ + sparse atomics; dummies self-reject (r2 == 0)
#pragma unroll
        for (int k = 0; k < GRP; ++k)
            lj_body(Ri[k], Rj[k], eps, s2, cut2, gi8[k], energy, forces);
    }
}

// ---------- fallback (R2 structure, 131 us) if ws/LDS insufficient ----------
#define PPT 8
__global__ void __launch_bounds__(256) lj_pairs_fb_kernel(
    const v4f* __restrict__ Rp,
    const v4i* __restrict__ idx_i4, const v4i* __restrict__ idx_j4,
    const float* __restrict__ eps_p, const float* __restrict__ sig_p,
    const float* __restrict__ cut_p,
    float* __restrict__ energy, float* __restrict__ forces, int n_oct)
{
    int t = blockIdx.x * blockDim.x + threadIdx.x;
    if (t >= n_oct) return;
    const float eps  = eps_p[0];
    const float sig  = sig_p[0];
    const float cut  = cut_p[0];
    const float s2   = sig * sig;
    const float cut2 = cut * cut;
    v4i ii0 = __builtin_nontemporal_load(idx_i4 + 2 * t);
    v4i ii1 = __builtin_nontemporal_load(idx_i4 + 2 * t + 1);
    v4i jj0 = __builtin_nontemporal_load(idx_j4 + 2 * t);
    v4i jj1 = __builtin_nontemporal_load(idx_j4 + 2 * t + 1);
    int is[PPT] = { ii0.x, ii0.y, ii0.z, ii0.w, ii1.x, ii1.y, ii1.z, ii1.w };
    int js[PPT] = { jj0.x, jj0.y, jj0.z, jj0.w, jj1.x, jj1.y, jj1.z, jj1.w };
    v4f Ri[PPT], Rj[PPT];
#pragma unroll
    for (int k = 0; k < PPT; ++k) Ri[k] = Rp[is[k]];
#pragma unroll
    for (int k = 0; k < PPT; ++k) Rj[k] = Rp[js[k]];
#pragma unroll
    for (int k = 0; k < PPT; ++k)
        lj_body(Ri[k], Rj[k], eps, s2, cut2, is[k], energy, forces);
}

__global__ void lj_pairs_fb_tail_kernel(
    const v4f* __restrict__ Rp,
    const int* __restrict__ idx_i, const int* __restrict__ idx_j,
    const float* __restrict__ eps_p, const float* __restrict__ sig_p,
    const float* __restrict__ cut_p,
    float* __restrict__ energy, float* __restrict__ forces,
    int start, int n_pairs)
{
    int p = start + blockIdx.x * blockDim.x + threadIdx.x;
    if (p >= n_pairs) return;
    const float eps = eps_p[0];
    const float sig = sig_p[0];
    const float cut = cut_p[0];
    lj_body(Rp[idx_i[p]], Rp[idx_j[p]], eps, sig * sig, cut * cut,
            idx_i[p], energy, forces);
}
// -----------------------------------------------------------------------------

extern "C" void kernel_launch(void* const* d_in, const int* in_sizes, int n_in,
                              void* d_out, int out_size, void* d_ws, size_t ws_size,
                              hipStream_t stream) {
    const float* R     = (const float*)d_in[0];
    const float* eps_p = (const float*)d_in[1];
    const float* sig_p = (const float*)d_in[2];
    const float* cut_p = (const float*)d_in[3];
    const int*   idx_i = (const int*)d_in[4];
    const int*   idx_j = (const int*)d_in[5];

    const int n_atoms = in_sizes[0] / 3;
    const int n_pairs = in_sizes[4];

    float* energy = (float*)d_out;
    float* forces = (float*)d_out + n_atoms;

    // d_out re-poisoned 0xAA before every timed call — zero it.
    (void)hipMemsetAsync(d_out, 0, (size_t)out_size * sizeof(float), stream);

    // ws layout: [Rp float4][packed 6-bit cell table]
    char* ws = (char*)d_ws;
    const size_t rp_b     = (((size_t)n_atoms * 16) + 255) & ~(size_t)255;
    const int    n_thr    = (n_atoms + 15) >> 4;
    const int    pk_words = 3 * n_thr + 1;               // +1 word read pad
    const size_t pk_b     = (((size_t)pk_words * 4) + 255) & ~(size_t)255;
    const size_t lds_b    = (((size_t)pk_words * 4) + 15) & ~(size_t)15;

    const bool have_rp    = ws_size >= rp_b;
    const bool use_filter = have_rp && (ws_size >= rp_b + pk_b)
                            && (lds_b <= 160000);

    v4f*      Rp     = (v4f*)ws;
    unsigned* packed = (unsigned*)(ws + rp_b);

    if (have_rp) {
        int blocks = (n_atoms + 255) / 256;
        pad_R_kernel<<<blocks, 256, 0, stream>>>(R, Rp, n_atoms);
    }

    if (use_filter) {
        int cblocks = (n_thr + 255) / 256;
        cell_kernel<<<cblocks, 256, 0, stream>>>(R, cut_p, packed, n_atoms);

        (void)hipFuncSetAttribute((const void*)lj_fused_kernel,
                                  hipFuncAttributeMaxDynamicSharedMemorySize,
                                  (int)lds_b);

        // one WG per CU: table loaded into LDS exactly once per CU
        int chunk = (((n_pairs + NWG_F - 1) / NWG_F) + GRP - 1) & ~(GRP - 1);
        lj_fused_kernel<<<NWG_F, WGT, lds_b, stream>>>(
            Rp, packed, idx_i, idx_j, eps_p, sig_p, cut_p,
            energy, forces, n_pairs, pk_words, chunk);
    } else {
        const int n_oct = n_pairs / PPT;
        const int start = n_oct * PPT;
        if (n_oct > 0) {
            int blocks = (n_oct + 255) / 256;
            lj_pairs_fb_kernel<<<blocks, 256, 0, stream>>>(
                Rp, (const v4i*)idx_i, (const v4i*)idx_j,
                eps_p, sig_p, cut_p, energy, forces, n_oct);
        }
        if (start < n_pairs) {
            lj_pairs_fb_tail_kernel<<<1, 64, 0, stream>>>(
                Rp, idx_i, idx_j, eps_p, sig_p, cut_p,
                energy, forces, start, n_pairs);
        }
    }
}